// Round 6
// baseline (631.557 us; speedup 1.0000x reference)
//
#include <hip/hip_runtime.h>
#include <hip/hip_bf16.h>

// GAT-GAE forward: 2x GATConv + normalize + MLP decoder. fp32 I/O, int32 edges.
// Round 6: (a) h1/h2 gather tables stored bf16 (halves gather bytes);
// (b) per-edge softmax weights precomputed in CSR order (ew1/ew2) so the
// gather loops are pure load+FMA; (c) 3-stage pipelined gathers.
//
// Workspace: hx[N*256]f | a_s1[N*4] | a_d1[N*4] | a_s2[N] | a_d2[N] |
//   ew1[Etot*4]f | ew2[Etot]f | h1b[N*256]bf16 | h2b[N*64]bf16 |
//   rowptr[N+1] | cursor[N] | col[Etot] | row[Etot]

#define IN_DIM   128
#define C1       256   // HEADS*HID
#define HEADS    4
#define HID      64
#define OUT_DIM  64

__device__ __forceinline__ float lrelu(float x) { return x > 0.f ? x : 0.2f * x; }
__device__ __forceinline__ float elu1(float x)  { return x > 0.f ? x : (__expf(x) - 1.f); }
__device__ __forceinline__ float expc(float x)  { return __expf(fminf(x, 60.f)); }
__device__ __forceinline__ float b2f(__hip_bfloat16 b) { return __bfloat162float(b); }
__device__ __forceinline__ __hip_bfloat16 f2b(float f) { return __float2bfloat16(f); }

// ================= Layer-1 GEMV: h1 = x @ W1 (bf16 out), logits =============
// block 256 = 4 waves; wave w handles 8 nodes; lane owns 4 channels.
__global__ __launch_bounds__(256) void gemm1_k(
    const float* __restrict__ x, const float* __restrict__ W1,
    const float* __restrict__ as1, const float* __restrict__ ad1,
    __hip_bfloat16* __restrict__ h1b, float* __restrict__ a_s1,
    float* __restrict__ a_d1, int N)
{
    __shared__ float xs[32 * 128];   // per wave region w*1024, layout [k*8+nb]
    const int t  = threadIdx.x;
    const int n0 = blockIdx.x * 32;
    for (int i = t; i < 32 * 128; i += 256) {
        const int nb_l = i >> 7, k = i & 127;
        const int n = min(n0 + nb_l, N - 1);
        xs[(nb_l >> 3) * 1024 + k * 8 + (nb_l & 7)] = x[(size_t)n * IN_DIM + k];
    }
    __syncthreads();
    const int w = t >> 6, l = t & 63;
    const float* xw = xs + w * 1024;
    float4 acc[8];
    #pragma unroll
    for (int nb = 0; nb < 8; ++nb) acc[nb] = make_float4(0.f, 0.f, 0.f, 0.f);
    const float4* W1v = (const float4*)W1;   // W1[k*256 + l*4] = W1v[k*64 + l]
    #pragma unroll 4
    for (int k = 0; k < 128; ++k) {
        const float4 wa = W1v[k * 64 + l];
        const float4 xa = *(const float4*)&xw[k * 8];
        const float4 xb = *(const float4*)&xw[k * 8 + 4];
        const float xv[8] = {xa.x, xa.y, xa.z, xa.w, xb.x, xb.y, xb.z, xb.w};
        #pragma unroll
        for (int nb = 0; nb < 8; ++nb) {
            acc[nb].x += xv[nb] * wa.x;
            acc[nb].y += xv[nb] * wa.y;
            acc[nb].z += xv[nb] * wa.z;
            acc[nb].w += xv[nb] * wa.w;
        }
    }
    const float4 s4 = *(const float4*)&as1[l * 4];
    const float4 d4 = *(const float4*)&ad1[l * 4];
    #pragma unroll
    for (int nb = 0; nb < 8; ++nb) {
        const int n = n0 + w * 8 + nb;
        if (n >= N) break;
        __hip_bfloat162* hp = (__hip_bfloat162*)(h1b + (size_t)n * C1 + l * 4);
        __hip_bfloat162 p0, p1;
        p0.x = f2b(acc[nb].x); p0.y = f2b(acc[nb].y);
        p1.x = f2b(acc[nb].z); p1.y = f2b(acc[nb].w);
        hp[0] = p0; hp[1] = p1;
        float vs = acc[nb].x * s4.x + acc[nb].y * s4.y + acc[nb].z * s4.z + acc[nb].w * s4.w;
        float vd = acc[nb].x * d4.x + acc[nb].y * d4.y + acc[nb].z * d4.z + acc[nb].w * d4.w;
        #pragma unroll
        for (int off = 1; off < 16; off <<= 1) {   // reduce within 16-lane head group
            vs += __shfl_xor(vs, off, 64);
            vd += __shfl_xor(vd, off, 64);
        }
        if ((l & 15) == 0) {
            a_s1[n * HEADS + (l >> 4)] = vs;
            a_d1[n * HEADS + (l >> 4)] = vd;
        }
    }
}

// ================= CSR build =================
__global__ void deg_k(const int* __restrict__ ei, int E, int Etot,
                      int* __restrict__ rowptr)
{
    const int e = blockIdx.x * blockDim.x + threadIdx.x;
    if (e >= Etot) return;
    const int d = (e < E) ? ei[E + e] : e - E;
    atomicAdd(&rowptr[1 + d], 1);
}

__global__ __launch_bounds__(1024) void scan_k(int* __restrict__ rowptr,
                                               int* __restrict__ cursor, int N)
{
    __shared__ int wsum[16];
    __shared__ int carry;
    const int t = threadIdx.x, lane = t & 63, wid = t >> 6;
    if (t == 0) carry = 0;
    __syncthreads();
    for (int base = 0; base < N; base += 1024) {
        const int i = base + t;
        const int v = (i < N) ? rowptr[1 + i] : 0;
        int sv = v;
        #pragma unroll
        for (int off = 1; off < 64; off <<= 1) {
            const int u = __shfl_up(sv, off, 64);
            if (lane >= off) sv += u;
        }
        if (lane == 63) wsum[wid] = sv;
        __syncthreads();
        if (wid == 0 && lane < 16) {
            int ws = wsum[lane];
            #pragma unroll
            for (int off = 1; off < 16; off <<= 1) {
                const int u = __shfl_up(ws, off, 16);
                if (lane >= off) ws += u;
            }
            wsum[lane] = ws;
        }
        __syncthreads();
        const int add = carry + (wid > 0 ? wsum[wid - 1] : 0);
        if (i < N) {
            rowptr[1 + i] = add + sv;
            cursor[i]     = add + sv - v;
        }
        __syncthreads();
        if (t == 0) carry += wsum[15];
        __syncthreads();
    }
}

__global__ void fill_k(const int* __restrict__ ei, int E, int Etot,
                       int* __restrict__ cursor, int* __restrict__ col,
                       int* __restrict__ row)
{
    const int e = blockIdx.x * blockDim.x + threadIdx.x;
    if (e >= Etot) return;
    int s, d;
    if (e < E) { s = ei[e]; d = ei[E + e]; } else { s = d = e - E; }
    const int pos = atomicAdd(&cursor[d], 1);
    col[pos] = s;
    row[pos] = d;
}

// ============ per-edge softmax weights in CSR order ============
__global__ void ew1_k(const int* __restrict__ col, const int* __restrict__ row,
                      const float* __restrict__ a_s1, const float* __restrict__ a_d1,
                      float* __restrict__ ew1, int Etot)
{
    const int p = blockIdx.x * blockDim.x + threadIdx.x;
    if (p >= Etot) return;
    const int s = col[p], d = row[p];
    const float4 sv = *(const float4*)&a_s1[s * 4];
    const float4 dv = *(const float4*)&a_d1[d * 4];
    float4 w;
    w.x = expc(lrelu(sv.x + dv.x));
    w.y = expc(lrelu(sv.y + dv.y));
    w.z = expc(lrelu(sv.z + dv.z));
    w.w = expc(lrelu(sv.w + dv.w));
    *(float4*)&ew1[(size_t)p * 4] = w;
}

__global__ void ew2_k(const int* __restrict__ col, const int* __restrict__ row,
                      const float* __restrict__ a_s2, const float* __restrict__ a_d2,
                      float* __restrict__ ew2, int Etot)
{
    const int p = blockIdx.x * blockDim.x + threadIdx.x;
    if (p >= Etot) return;
    ew2[p] = expc(lrelu(a_s2[col[p]] + a_d2[row[p]]));
}

// ====== Layer-1 aggregate (weighted mean + bias + ELU), 3-stage pipeline =====
// block 256 per dst node; thread t = channel t, head t>>6.
__global__ __launch_bounds__(256) void agg1_k(
    const int* __restrict__ rowptr, const int* __restrict__ col,
    const float* __restrict__ ew1, const __hip_bfloat16* __restrict__ h1b,
    const float* __restrict__ b1, float* __restrict__ hout)
{
    const int d = blockIdx.x, t = threadIdx.x, head = t >> 6;
    const int beg = rowptr[d], end = rowptr[d + 1];
    float acc = 0.f, wsum = 0.f;
    int   sB  = col[beg];                       // s for iter j
    float wA  = ew1[(size_t)beg * 4 + head];
    float hvA = b2f(h1b[(size_t)sB * C1 + t]);
    sB = (beg + 1 < end) ? col[beg + 1] : 0;
    for (int j = beg; j < end; ++j) {
        const int sC = (j + 2 < end) ? col[j + 2] : 0;           // 2-ahead
        float hvB = 0.f, wB = 0.f;
        if (j + 1 < end) {
            wB  = ew1[(size_t)(j + 1) * 4 + head];
            hvB = b2f(h1b[(size_t)sB * C1 + t]);                 // addr ready
        }
        acc  += hvA * wA;
        wsum += wA;
        sB = sC; wA = wB; hvA = hvB;
    }
    hout[(size_t)d * C1 + t] = elu1(acc / (wsum + 1e-16f) + b1[t]);
}

// ================= Layer-2 GEMV: h2 = h @ W2 (bf16 out), logits ==============
__global__ __launch_bounds__(256) void gemm2_k(
    const float* __restrict__ h, const float* __restrict__ W2,
    const float* __restrict__ as2, const float* __restrict__ ad2,
    __hip_bfloat16* __restrict__ h2b, float* __restrict__ a_s2,
    float* __restrict__ a_d2, int N)
{
    __shared__ float hs[32 * 256];   // 32 KB; wave region w*2048, [k*8+nb]
    const int t = threadIdx.x;
    const int n0 = blockIdx.x * 32;
    for (int i = t; i < 32 * 256; i += 256) {
        const int nb_l = i >> 8, k = i & 255;
        const int n = min(n0 + nb_l, N - 1);
        hs[(nb_l >> 3) * 2048 + k * 8 + (nb_l & 7)] = h[(size_t)n * C1 + k];
    }
    __syncthreads();
    const int w = t >> 6, l = t & 63;
    const float* hw = hs + w * 2048;
    float acc[8] = {0.f, 0.f, 0.f, 0.f, 0.f, 0.f, 0.f, 0.f};
    #pragma unroll 4
    for (int k = 0; k < 256; ++k) {
        const float wv = W2[k * OUT_DIM + l];
        const float4 xa = *(const float4*)&hw[k * 8];
        const float4 xb = *(const float4*)&hw[k * 8 + 4];
        acc[0] += xa.x * wv; acc[1] += xa.y * wv;
        acc[2] += xa.z * wv; acc[3] += xa.w * wv;
        acc[4] += xb.x * wv; acc[5] += xb.y * wv;
        acc[6] += xb.z * wv; acc[7] += xb.w * wv;
    }
    const float sv2 = as2[l], dv2 = ad2[l];
    #pragma unroll
    for (int nb = 0; nb < 8; ++nb) {
        const int n = n0 + w * 8 + nb;
        if (n >= N) break;
        h2b[(size_t)n * OUT_DIM + l] = f2b(acc[nb]);
        float vs = acc[nb] * sv2, vd = acc[nb] * dv2;
        #pragma unroll
        for (int off = 1; off < 64; off <<= 1) {
            vs += __shfl_xor(vs, off, 64);
            vd += __shfl_xor(vd, off, 64);
        }
        if (l == 0) { a_s2[n] = vs; a_d2[n] = vd; }
    }
}

// ====== Layer-2 aggregate + bias + L2-normalize -> z (in d_out) ======
__global__ __launch_bounds__(64) void agg2_k(
    const int* __restrict__ rowptr, const int* __restrict__ col,
    const float* __restrict__ ew2, const __hip_bfloat16* __restrict__ h2b,
    const float* __restrict__ b2, float* __restrict__ zout)
{
    const int d = blockIdx.x, t = threadIdx.x;
    const int beg = rowptr[d], end = rowptr[d + 1];
    float acc = 0.f, wsum = 0.f;
    int   sB  = col[beg];
    float wA  = ew2[beg];
    float hvA = b2f(h2b[(size_t)sB * OUT_DIM + t]);
    sB = (beg + 1 < end) ? col[beg + 1] : 0;
    for (int j = beg; j < end; ++j) {
        const int sC = (j + 2 < end) ? col[j + 2] : 0;
        float hvB = 0.f, wB = 0.f;
        if (j + 1 < end) {
            wB  = ew2[j + 1];
            hvB = b2f(h2b[(size_t)sB * OUT_DIM + t]);
        }
        acc  += hvA * wA;
        wsum += wA;
        sB = sC; wA = wB; hvA = hvB;
    }
    float z = acc / (wsum + 1e-16f) + b2[t];
    float sq = z * z;
    #pragma unroll
    for (int off = 1; off < 64; off <<= 1) sq += __shfl_xor(sq, off, 64);
    z /= fmaxf(sqrtf(sq), 1e-12f);
    zout[(size_t)d * OUT_DIM + t] = z;
}

// ================= Decoder: x_hat = elu(z@dW1+db1)@dW2+db2 =================
__global__ __launch_bounds__(256) void dec_k(
    const float* __restrict__ z,
    const float* __restrict__ dW1, const float* __restrict__ db1,
    const float* __restrict__ dW2, const float* __restrict__ db2,
    float* __restrict__ xhat, int N)
{
    __shared__ float zs[32 * 64];
    __shared__ float ts[32 * 64];
    const int t = threadIdx.x;
    const int n0 = blockIdx.x * 32;
    for (int i = t; i < 32 * 64; i += 256) {
        const int nb_l = i >> 6, k = i & 63;
        const int n = min(n0 + nb_l, N - 1);
        zs[(nb_l >> 3) * 512 + k * 8 + (nb_l & 7)] = z[(size_t)n * OUT_DIM + k];
    }
    __syncthreads();
    const int w = t >> 6, l = t & 63;
    const float* zw = zs + w * 512;
    float* tw = ts + w * 512;
    float acc[8] = {0.f, 0.f, 0.f, 0.f, 0.f, 0.f, 0.f, 0.f};
    #pragma unroll 4
    for (int k = 0; k < 64; ++k) {
        const float wv = dW1[k * HID + l];
        const float4 xa = *(const float4*)&zw[k * 8];
        const float4 xb = *(const float4*)&zw[k * 8 + 4];
        acc[0] += xa.x * wv; acc[1] += xa.y * wv;
        acc[2] += xa.z * wv; acc[3] += xa.w * wv;
        acc[4] += xb.x * wv; acc[5] += xb.y * wv;
        acc[6] += xb.z * wv; acc[7] += xb.w * wv;
    }
    const float bb = db1[l];
    #pragma unroll
    for (int nb = 0; nb < 8; ++nb) tw[l * 8 + nb] = elu1(acc[nb] + bb);
    __syncthreads();
    float a0[8] = {0.f, 0.f, 0.f, 0.f, 0.f, 0.f, 0.f, 0.f};
    float a1[8] = {0.f, 0.f, 0.f, 0.f, 0.f, 0.f, 0.f, 0.f};
    #pragma unroll 2
    for (int k = 0; k < 64; ++k) {
        const float w0 = dW2[k * IN_DIM + l];
        const float w1 = dW2[k * IN_DIM + 64 + l];
        const float4 xa = *(const float4*)&tw[k * 8];
        const float4 xb = *(const float4*)&tw[k * 8 + 4];
        const float xv[8] = {xa.x, xa.y, xa.z, xa.w, xb.x, xb.y, xb.z, xb.w};
        #pragma unroll
        for (int nb = 0; nb < 8; ++nb) {
            a0[nb] += xv[nb] * w0;
            a1[nb] += xv[nb] * w1;
        }
    }
    const float bb0 = db2[l], bb1 = db2[64 + l];
    #pragma unroll
    for (int nb = 0; nb < 8; ++nb) {
        const int n = n0 + w * 8 + nb;
        if (n >= N) break;
        xhat[(size_t)n * IN_DIM + l]      = a0[nb] + bb0;
        xhat[(size_t)n * IN_DIM + 64 + l] = a1[nb] + bb1;
    }
}

extern "C" void kernel_launch(void* const* d_in, const int* in_sizes, int n_in,
                              void* d_out, int out_size, void* d_ws, size_t ws_size,
                              hipStream_t stream)
{
    const float* x   = (const float*)d_in[0];
    const int*   ei  = (const int*)d_in[1];
    const float* W1  = (const float*)d_in[2];
    const float* as1 = (const float*)d_in[3];
    const float* ad1 = (const float*)d_in[4];
    const float* b1  = (const float*)d_in[5];
    const float* W2  = (const float*)d_in[6];
    const float* as2 = (const float*)d_in[7];
    const float* ad2 = (const float*)d_in[8];
    const float* b2  = (const float*)d_in[9];
    const float* dW1 = (const float*)d_in[10];
    const float* db1 = (const float*)d_in[11];
    const float* dW2 = (const float*)d_in[12];
    const float* db2 = (const float*)d_in[13];

    const int N    = in_sizes[0] / IN_DIM;
    const int E    = in_sizes[1] / 2;
    const int Etot = E + N;

    float* ws = (float*)d_ws;
    float* hx   = ws;                            // N*256 fp32
    float* a_s1 = hx   + (size_t)N * C1;         // N*4
    float* a_d1 = a_s1 + (size_t)N * HEADS;      // N*4
    float* a_s2 = a_d1 + (size_t)N * HEADS;      // N
    float* a_d2 = a_s2 + (size_t)N;              // N
    float* ew1  = a_d2 + (size_t)N;              // Etot*4
    float* ew2  = ew1  + (size_t)Etot * HEADS;   // Etot
    __hip_bfloat16* h1b = (__hip_bfloat16*)(ew2 + (size_t)Etot);  // N*256 bf16
    __hip_bfloat16* h2b = h1b + (size_t)N * C1;                    // N*64 bf16
    int* rowptr = (int*)(h2b + (size_t)N * OUT_DIM);               // N+1
    int* cursor = rowptr + (N + 1);              // N
    int* col    = cursor + N;                    // Etot
    int* row    = col    + Etot;                 // Etot

    const size_t needed = ((size_t)N * 428 + 1 + (size_t)Etot * 7) * 4;
    if (ws_size < needed) return;  // loud failure signature (absmax ~0.543)

    hipMemsetAsync(rowptr, 0, (size_t)(N + 1) * sizeof(int), stream);

    const int nblk = (N + 31) / 32;
    const int eblk = (Etot + 255) / 256;
    gemm1_k<<<nblk, 256, 0, stream>>>(x, W1, as1, ad1, h1b, a_s1, a_d1, N);
    deg_k  <<<eblk, 256, 0, stream>>>(ei, E, Etot, rowptr);
    scan_k <<<1, 1024, 0, stream>>>(rowptr, cursor, N);
    fill_k <<<eblk, 256, 0, stream>>>(ei, E, Etot, cursor, col, row);
    ew1_k  <<<eblk, 256, 0, stream>>>(col, row, a_s1, a_d1, ew1, Etot);
    agg1_k <<<N, 256, 0, stream>>>(rowptr, col, ew1, h1b, b1, hx);
    gemm2_k<<<nblk, 256, 0, stream>>>(hx, W2, as2, ad2, h2b, a_s2, a_d2, N);
    ew2_k  <<<eblk, 256, 0, stream>>>(col, row, a_s2, a_d2, ew2, Etot);
    agg2_k <<<N, 64, 0, stream>>>(rowptr, col, ew2, h2b, b2, (float*)d_out);
    dec_k  <<<nblk, 256, 0, stream>>>((const float*)d_out, dW1, db1, dW2, db2,
                                      (float*)d_out + (size_t)N * OUT_DIM, N);
}

// Round 7
// 452.139 us; speedup vs baseline: 1.3968x; 1.3968x over previous
//
#include <hip/hip_runtime.h>
#include <hip/hip_bf16.h>

// GAT-GAE forward: 2x GATConv + normalize + MLP decoder. fp32 I/O, int32 edges.
// Round 7: latency-bound agg fixed — per-tile index/weight staged in registers
// (coalesced), inner loop broadcasts via __shfl and issues 8 INDEPENDENT
// gathers per step (no load->address chains). ew1 transposed to [head][Etot].
// Single-block scan replaced with 3-phase multi-block scan.
//
// Workspace: hx[N*256]f | a_s1[4N] | a_d1[4N] | a_s2[N] | a_d2[N] |
//   ew1[4*Etot]f (plane-per-head) | ew2[Etot]f | h1b[N*256]bf16 | h2b[N*64]bf16
//   | rowptr[N+1] | cursor[N] | col[Etot] | row[Etot] | psum[256]

#define IN_DIM   128
#define C1       256   // HEADS*HID
#define HEADS    4
#define HID      64
#define OUT_DIM  64

__device__ __forceinline__ float lrelu(float x) { return x > 0.f ? x : 0.2f * x; }
__device__ __forceinline__ float elu1(float x)  { return x > 0.f ? x : (__expf(x) - 1.f); }
__device__ __forceinline__ float expc(float x)  { return __expf(fminf(x, 60.f)); }
__device__ __forceinline__ float b2f(__hip_bfloat16 b) { return __bfloat162float(b); }
__device__ __forceinline__ __hip_bfloat16 f2b(float f) { return __float2bfloat16(f); }

// ================= Layer-1 GEMV: h1 = x @ W1 (bf16 out), logits =============
__global__ __launch_bounds__(256) void gemm1_k(
    const float* __restrict__ x, const float* __restrict__ W1,
    const float* __restrict__ as1, const float* __restrict__ ad1,
    __hip_bfloat16* __restrict__ h1b, float* __restrict__ a_s1,
    float* __restrict__ a_d1, int N)
{
    __shared__ float xs[32 * 128];   // per wave region w*1024, layout [k*8+nb]
    const int t  = threadIdx.x;
    const int n0 = blockIdx.x * 32;
    for (int i = t; i < 32 * 128; i += 256) {
        const int nb_l = i >> 7, k = i & 127;
        const int n = min(n0 + nb_l, N - 1);
        xs[(nb_l >> 3) * 1024 + k * 8 + (nb_l & 7)] = x[(size_t)n * IN_DIM + k];
    }
    __syncthreads();
    const int w = t >> 6, l = t & 63;
    const float* xw = xs + w * 1024;
    float4 acc[8];
    #pragma unroll
    for (int nb = 0; nb < 8; ++nb) acc[nb] = make_float4(0.f, 0.f, 0.f, 0.f);
    const float4* W1v = (const float4*)W1;   // W1[k*256 + l*4] = W1v[k*64 + l]
    #pragma unroll 4
    for (int k = 0; k < 128; ++k) {
        const float4 wa = W1v[k * 64 + l];
        const float4 xa = *(const float4*)&xw[k * 8];
        const float4 xb = *(const float4*)&xw[k * 8 + 4];
        const float xv[8] = {xa.x, xa.y, xa.z, xa.w, xb.x, xb.y, xb.z, xb.w};
        #pragma unroll
        for (int nb = 0; nb < 8; ++nb) {
            acc[nb].x += xv[nb] * wa.x;
            acc[nb].y += xv[nb] * wa.y;
            acc[nb].z += xv[nb] * wa.z;
            acc[nb].w += xv[nb] * wa.w;
        }
    }
    const float4 s4 = *(const float4*)&as1[l * 4];
    const float4 d4 = *(const float4*)&ad1[l * 4];
    #pragma unroll
    for (int nb = 0; nb < 8; ++nb) {
        const int n = n0 + w * 8 + nb;
        if (n >= N) break;
        __hip_bfloat162* hp = (__hip_bfloat162*)(h1b + (size_t)n * C1 + l * 4);
        __hip_bfloat162 p0, p1;
        p0.x = f2b(acc[nb].x); p0.y = f2b(acc[nb].y);
        p1.x = f2b(acc[nb].z); p1.y = f2b(acc[nb].w);
        hp[0] = p0; hp[1] = p1;
        float vs = acc[nb].x * s4.x + acc[nb].y * s4.y + acc[nb].z * s4.z + acc[nb].w * s4.w;
        float vd = acc[nb].x * d4.x + acc[nb].y * d4.y + acc[nb].z * d4.z + acc[nb].w * d4.w;
        #pragma unroll
        for (int off = 1; off < 16; off <<= 1) {
            vs += __shfl_xor(vs, off, 64);
            vd += __shfl_xor(vd, off, 64);
        }
        if ((l & 15) == 0) {
            a_s1[n * HEADS + (l >> 4)] = vs;
            a_d1[n * HEADS + (l >> 4)] = vd;
        }
    }
}

// ================= CSR build =================
__global__ void deg_k(const int* __restrict__ ei, int E, int Etot,
                      int* __restrict__ rowptr)
{
    const int e = blockIdx.x * blockDim.x + threadIdx.x;
    if (e >= Etot) return;
    const int d = (e < E) ? ei[E + e] : e - E;
    atomicAdd(&rowptr[1 + d], 1);
}

// block-wide inclusive scan helper (256 threads)
__device__ __forceinline__ int blk_incl_scan(int v, int t) {
    __shared__ int wsum[4];
    const int lane = t & 63, wid = t >> 6;
    int s = v;
    #pragma unroll
    for (int off = 1; off < 64; off <<= 1) {
        const int u = __shfl_up(s, off, 64);
        if (lane >= off) s += u;
    }
    if (lane == 63) wsum[wid] = s;
    __syncthreads();
    int add = 0;
    #pragma unroll
    for (int k = 0; k < 4; ++k) if (k < wid) add += wsum[k];
    __syncthreads();
    return s + add;
}

// Phase A: per-chunk (256 elems) sums of deg (stored at rowptr[1+i])
__global__ __launch_bounds__(256) void scanA_k(const int* __restrict__ rowptr,
                                               int* __restrict__ psum, int N)
{
    const int t = threadIdx.x;
    const int i = blockIdx.x * 256 + t;
    int v = (i < N) ? rowptr[1 + i] : 0;
    #pragma unroll
    for (int off = 1; off < 64; off <<= 1) v += __shfl_xor(v, off, 64);
    __shared__ int ws[4];
    if ((t & 63) == 0) ws[t >> 6] = v;
    __syncthreads();
    if (t == 0) psum[blockIdx.x] = ws[0] + ws[1] + ws[2] + ws[3];
}

// Phase B: single block exclusive-scans psum[SC] in place (SC <= 256)
__global__ __launch_bounds__(256) void scanB_k(int* __restrict__ psum, int SC)
{
    const int t = threadIdx.x;
    const int v = (t < SC) ? psum[t] : 0;
    const int inc = blk_incl_scan(v, t);
    if (t < SC) psum[t] = inc - v;   // exclusive
}

// Phase C: local scan + chunk offset -> rowptr (inclusive at [1+i]), cursor
__global__ __launch_bounds__(256) void scanC_k(int* __restrict__ rowptr,
                                               int* __restrict__ cursor,
                                               const int* __restrict__ psum, int N)
{
    const int t = threadIdx.x;
    const int i = blockIdx.x * 256 + t;
    const int v = (i < N) ? rowptr[1 + i] : 0;
    const int inc = blk_incl_scan(v, t);
    const int base = psum[blockIdx.x];
    if (i < N) {
        rowptr[1 + i] = base + inc;
        cursor[i]     = base + inc - v;
    }
}

__global__ void fill_k(const int* __restrict__ ei, int E, int Etot,
                       int* __restrict__ cursor, int* __restrict__ col,
                       int* __restrict__ row)
{
    const int e = blockIdx.x * blockDim.x + threadIdx.x;
    if (e >= Etot) return;
    int s, d;
    if (e < E) { s = ei[e]; d = ei[E + e]; } else { s = d = e - E; }
    const int pos = atomicAdd(&cursor[d], 1);
    col[pos] = s;
    row[pos] = d;
}

// ============ per-edge softmax weights, CSR order, head-plane layout ========
__global__ void ew1_k(const int* __restrict__ col, const int* __restrict__ row,
                      const float* __restrict__ a_s1, const float* __restrict__ a_d1,
                      float* __restrict__ ew1, int Etot)
{
    const int p = blockIdx.x * blockDim.x + threadIdx.x;
    if (p >= Etot) return;
    const int s = col[p], d = row[p];
    const float4 sv = *(const float4*)&a_s1[s * 4];
    const float4 dv = *(const float4*)&a_d1[d * 4];
    ew1[p]                    = expc(lrelu(sv.x + dv.x));
    ew1[(size_t)Etot + p]     = expc(lrelu(sv.y + dv.y));
    ew1[(size_t)2 * Etot + p] = expc(lrelu(sv.z + dv.z));
    ew1[(size_t)3 * Etot + p] = expc(lrelu(sv.w + dv.w));
}

__global__ void ew2_k(const int* __restrict__ col, const int* __restrict__ row,
                      const float* __restrict__ a_s2, const float* __restrict__ a_d2,
                      float* __restrict__ ew2, int Etot)
{
    const int p = blockIdx.x * blockDim.x + threadIdx.x;
    if (p >= Etot) return;
    ew2[p] = expc(lrelu(a_s2[col[p]] + a_d2[row[p]]));
}

// ====== Layer-1 aggregate: shfl-broadcast, 8 independent gathers/step ======
// block 256 per dst node; thread t = channel t, head t>>6.
__global__ __launch_bounds__(256) void agg1_k(
    const int* __restrict__ rowptr, const int* __restrict__ col,
    const float* __restrict__ ew1, const __hip_bfloat16* __restrict__ h1b,
    const float* __restrict__ b1, float* __restrict__ hout, int Etot)
{
    const int d = blockIdx.x, t = threadIdx.x, head = t >> 6, lane = t & 63;
    const int beg = rowptr[d], end = rowptr[d + 1];
    const float* ewp = ew1 + (size_t)head * Etot;
    float acc = 0.f, wsum = 0.f;
    for (int t0 = beg; t0 < end; t0 += 64) {
        const int p = t0 + lane;
        const int  sidx = (p < end) ? col[p] : 0;
        const float wv  = (p < end) ? ewp[p] : 0.f;   // padded lanes weight 0
        const int m = min(64, end - t0);
        for (int j = 0; j < m; j += 8) {
            #pragma unroll
            for (int u = 0; u < 8; ++u) {
                const int   su = __shfl(sidx, j + u, 64);
                const float wu = __shfl(wv,   j + u, 64);
                acc  = fmaf(b2f(h1b[(size_t)su * C1 + t]), wu, acc);
                wsum += wu;
            }
        }
    }
    hout[(size_t)d * C1 + t] = elu1(acc / (wsum + 1e-16f) + b1[t]);
}

// ================= Layer-2 GEMV: h2 = h @ W2 (bf16 out), logits ==============
__global__ __launch_bounds__(256) void gemm2_k(
    const float* __restrict__ h, const float* __restrict__ W2,
    const float* __restrict__ as2, const float* __restrict__ ad2,
    __hip_bfloat16* __restrict__ h2b, float* __restrict__ a_s2,
    float* __restrict__ a_d2, int N)
{
    __shared__ float hs[32 * 256];   // 32 KB; wave region w*2048, [k*8+nb]
    const int t = threadIdx.x;
    const int n0 = blockIdx.x * 32;
    for (int i = t; i < 32 * 256; i += 256) {
        const int nb_l = i >> 8, k = i & 255;
        const int n = min(n0 + nb_l, N - 1);
        hs[(nb_l >> 3) * 2048 + k * 8 + (nb_l & 7)] = h[(size_t)n * C1 + k];
    }
    __syncthreads();
    const int w = t >> 6, l = t & 63;
    const float* hw = hs + w * 2048;
    float acc[8] = {0.f, 0.f, 0.f, 0.f, 0.f, 0.f, 0.f, 0.f};
    #pragma unroll 4
    for (int k = 0; k < 256; ++k) {
        const float wv = W2[k * OUT_DIM + l];
        const float4 xa = *(const float4*)&hw[k * 8];
        const float4 xb = *(const float4*)&hw[k * 8 + 4];
        acc[0] += xa.x * wv; acc[1] += xa.y * wv;
        acc[2] += xa.z * wv; acc[3] += xa.w * wv;
        acc[4] += xb.x * wv; acc[5] += xb.y * wv;
        acc[6] += xb.z * wv; acc[7] += xb.w * wv;
    }
    const float sv2 = as2[l], dv2 = ad2[l];
    #pragma unroll
    for (int nb = 0; nb < 8; ++nb) {
        const int n = n0 + w * 8 + nb;
        if (n >= N) break;
        h2b[(size_t)n * OUT_DIM + l] = f2b(acc[nb]);
        float vs = acc[nb] * sv2, vd = acc[nb] * dv2;
        #pragma unroll
        for (int off = 1; off < 64; off <<= 1) {
            vs += __shfl_xor(vs, off, 64);
            vd += __shfl_xor(vd, off, 64);
        }
        if (l == 0) { a_s2[n] = vs; a_d2[n] = vd; }
    }
}

// ====== Layer-2 aggregate + bias + L2-normalize -> z; 4 nodes/block ======
__global__ __launch_bounds__(256) void agg2_k(
    const int* __restrict__ rowptr, const int* __restrict__ col,
    const float* __restrict__ ew2, const __hip_bfloat16* __restrict__ h2b,
    const float* __restrict__ b2, float* __restrict__ zout, int N)
{
    const int t = threadIdx.x, wid = t >> 6, l = t & 63;
    const int n = blockIdx.x * 4 + wid;
    if (n >= N) return;
    const int beg = rowptr[n], end = rowptr[n + 1];
    float acc = 0.f, wsum = 0.f;
    for (int t0 = beg; t0 < end; t0 += 64) {
        const int p = t0 + l;
        const int  sidx = (p < end) ? col[p] : 0;
        const float wv  = (p < end) ? ew2[p] : 0.f;
        const int m = min(64, end - t0);
        for (int j = 0; j < m; j += 8) {
            #pragma unroll
            for (int u = 0; u < 8; ++u) {
                const int   su = __shfl(sidx, j + u, 64);
                const float wu = __shfl(wv,   j + u, 64);
                acc  = fmaf(b2f(h2b[(size_t)su * OUT_DIM + l]), wu, acc);
                wsum += wu;
            }
        }
    }
    float z = acc / (wsum + 1e-16f) + b2[l];
    float sq = z * z;
    #pragma unroll
    for (int off = 1; off < 64; off <<= 1) sq += __shfl_xor(sq, off, 64);
    z /= fmaxf(sqrtf(sq), 1e-12f);
    zout[(size_t)n * OUT_DIM + l] = z;
}

// ================= Decoder: x_hat = elu(z@dW1+db1)@dW2+db2 =================
__global__ __launch_bounds__(256) void dec_k(
    const float* __restrict__ z,
    const float* __restrict__ dW1, const float* __restrict__ db1,
    const float* __restrict__ dW2, const float* __restrict__ db2,
    float* __restrict__ xhat, int N)
{
    __shared__ float zs[32 * 64];
    __shared__ float ts[32 * 64];
    const int t = threadIdx.x;
    const int n0 = blockIdx.x * 32;
    for (int i = t; i < 32 * 64; i += 256) {
        const int nb_l = i >> 6, k = i & 63;
        const int n = min(n0 + nb_l, N - 1);
        zs[(nb_l >> 3) * 512 + k * 8 + (nb_l & 7)] = z[(size_t)n * OUT_DIM + k];
    }
    __syncthreads();
    const int w = t >> 6, l = t & 63;
    const float* zw = zs + w * 512;
    float* tw = ts + w * 512;
    float acc[8] = {0.f, 0.f, 0.f, 0.f, 0.f, 0.f, 0.f, 0.f};
    #pragma unroll 4
    for (int k = 0; k < 64; ++k) {
        const float wv = dW1[k * HID + l];
        const float4 xa = *(const float4*)&zw[k * 8];
        const float4 xb = *(const float4*)&zw[k * 8 + 4];
        acc[0] += xa.x * wv; acc[1] += xa.y * wv;
        acc[2] += xa.z * wv; acc[3] += xa.w * wv;
        acc[4] += xb.x * wv; acc[5] += xb.y * wv;
        acc[6] += xb.z * wv; acc[7] += xb.w * wv;
    }
    const float bb = db1[l];
    #pragma unroll
    for (int nb = 0; nb < 8; ++nb) tw[l * 8 + nb] = elu1(acc[nb] + bb);
    __syncthreads();
    float a0[8] = {0.f, 0.f, 0.f, 0.f, 0.f, 0.f, 0.f, 0.f};
    float a1[8] = {0.f, 0.f, 0.f, 0.f, 0.f, 0.f, 0.f, 0.f};
    #pragma unroll 2
    for (int k = 0; k < 64; ++k) {
        const float w0 = dW2[k * IN_DIM + l];
        const float w1 = dW2[k * IN_DIM + 64 + l];
        const float4 xa = *(const float4*)&tw[k * 8];
        const float4 xb = *(const float4*)&tw[k * 8 + 4];
        const float xv[8] = {xa.x, xa.y, xa.z, xa.w, xb.x, xb.y, xb.z, xb.w};
        #pragma unroll
        for (int nb = 0; nb < 8; ++nb) {
            a0[nb] += xv[nb] * w0;
            a1[nb] += xv[nb] * w1;
        }
    }
    const float bb0 = db2[l], bb1 = db2[64 + l];
    #pragma unroll
    for (int nb = 0; nb < 8; ++nb) {
        const int n = n0 + w * 8 + nb;
        if (n >= N) break;
        xhat[(size_t)n * IN_DIM + l]      = a0[nb] + bb0;
        xhat[(size_t)n * IN_DIM + 64 + l] = a1[nb] + bb1;
    }
}

extern "C" void kernel_launch(void* const* d_in, const int* in_sizes, int n_in,
                              void* d_out, int out_size, void* d_ws, size_t ws_size,
                              hipStream_t stream)
{
    const float* x   = (const float*)d_in[0];
    const int*   ei  = (const int*)d_in[1];
    const float* W1  = (const float*)d_in[2];
    const float* as1 = (const float*)d_in[3];
    const float* ad1 = (const float*)d_in[4];
    const float* b1  = (const float*)d_in[5];
    const float* W2  = (const float*)d_in[6];
    const float* as2 = (const float*)d_in[7];
    const float* ad2 = (const float*)d_in[8];
    const float* b2  = (const float*)d_in[9];
    const float* dW1 = (const float*)d_in[10];
    const float* db1 = (const float*)d_in[11];
    const float* dW2 = (const float*)d_in[12];
    const float* db2 = (const float*)d_in[13];

    const int N    = in_sizes[0] / IN_DIM;
    const int E    = in_sizes[1] / 2;
    const int Etot = E + N;

    float* ws = (float*)d_ws;
    float* hx   = ws;                            // N*256 fp32
    float* a_s1 = hx   + (size_t)N * C1;         // N*4
    float* a_d1 = a_s1 + (size_t)N * HEADS;      // N*4
    float* a_s2 = a_d1 + (size_t)N * HEADS;      // N
    float* a_d2 = a_s2 + (size_t)N;              // N
    float* ew1  = a_d2 + (size_t)N;              // Etot*4 (head planes)
    float* ew2  = ew1  + (size_t)Etot * HEADS;   // Etot
    __hip_bfloat16* h1b = (__hip_bfloat16*)(ew2 + (size_t)Etot);  // N*256 bf16
    __hip_bfloat16* h2b = h1b + (size_t)N * C1;                    // N*64 bf16
    int* rowptr = (int*)(h2b + (size_t)N * OUT_DIM);               // N+1
    int* cursor = rowptr + (N + 1);              // N
    int* col    = cursor + N;                    // Etot
    int* row    = col    + Etot;                 // Etot
    int* psum   = row    + Etot;                 // 256

    const size_t needed = ((size_t)N * 428 + 257 + (size_t)Etot * 7) * 4;
    if (ws_size < needed) return;  // loud failure signature (absmax ~0.543)

    hipMemsetAsync(rowptr, 0, (size_t)(N + 1) * sizeof(int), stream);

    const int nblk = (N + 31) / 32;
    const int eblk = (Etot + 255) / 256;
    const int SC   = (N + 255) / 256;            // 196 for N=50k (<=256 req'd)
    gemm1_k<<<nblk, 256, 0, stream>>>(x, W1, as1, ad1, h1b, a_s1, a_d1, N);
    deg_k  <<<eblk, 256, 0, stream>>>(ei, E, Etot, rowptr);
    scanA_k<<<SC, 256, 0, stream>>>(rowptr, psum, N);
    scanB_k<<<1, 256, 0, stream>>>(psum, SC);
    scanC_k<<<SC, 256, 0, stream>>>(rowptr, cursor, psum, N);
    fill_k <<<eblk, 256, 0, stream>>>(ei, E, Etot, cursor, col, row);
    ew1_k  <<<eblk, 256, 0, stream>>>(col, row, a_s1, a_d1, ew1, Etot);
    agg1_k <<<N, 256, 0, stream>>>(rowptr, col, ew1, h1b, b1, hx, Etot);
    gemm2_k<<<nblk, 256, 0, stream>>>(hx, W2, as2, ad2, h2b, a_s2, a_d2, N);
    ew2_k  <<<eblk, 256, 0, stream>>>(col, row, a_s2, a_d2, ew2, Etot);
    agg2_k <<<(N + 3) / 4, 256, 0, stream>>>(rowptr, col, ew2, h2b, b2,
                                             (float*)d_out, N);
    dec_k  <<<nblk, 256, 0, stream>>>((const float*)d_out, dW1, db1, dW2, db2,
                                      (float*)d_out + (size_t)N * OUT_DIM, N);
}

// Round 8
// 441.292 us; speedup vs baseline: 1.4312x; 1.0246x over previous
//
#include <hip/hip_runtime.h>
#include <hip/hip_bf16.h>

// GAT-GAE forward: 2x GATConv + normalize + MLP decoder. fp32 I/O, int32 edges.
// Round 8: one wave per node in agg1 (lane = 4 channels, ushort4 gather) and
// 2-edges-per-wave-step agg2 (lane = 2 channels) — ~2.6x fewer dynamic
// instructions on the edge loops at identical gather bytes. ew1 interleaved
// [p*4+h]; hx stored bf16 between agg1 and gemm2.
//
// Workspace: hx[N*256]bf16(in f32 slot) | a_s1[4N] | a_d1[4N] | a_s2[N] |
//   a_d2[N] | ew1[4*Etot] | ew2[Etot] | h1b[N*256]u16 | h2b[N*64]u16 |
//   rowptr[N+1] | cursor[N] | col[Etot] | row[Etot] | psum[256]

#define IN_DIM   128
#define C1       256   // HEADS*HID
#define HEADS    4
#define HID      64
#define OUT_DIM  64

__device__ __forceinline__ float lrelu(float x) { return x > 0.f ? x : 0.2f * x; }
__device__ __forceinline__ float elu1(float x)  { return x > 0.f ? x : (__expf(x) - 1.f); }
__device__ __forceinline__ float expc(float x)  { return __expf(fminf(x, 60.f)); }
// raw bf16 <-> f32 (RNE), table dtype is unsigned short
__device__ __forceinline__ float bfu(unsigned int u) {
    union { unsigned int i; float f; } c; c.i = u << 16; return c.f;
}
__device__ __forceinline__ unsigned short pk(float f) {
    union { float f; unsigned int i; } c; c.f = f;
    return (unsigned short)((c.i + 0x7fffu + ((c.i >> 16) & 1u)) >> 16);
}

// ================= Layer-1 GEMV: h1 = x @ W1 (bf16 table), logits ===========
__global__ __launch_bounds__(256) void gemm1_k(
    const float* __restrict__ x, const float* __restrict__ W1,
    const float* __restrict__ as1, const float* __restrict__ ad1,
    unsigned short* __restrict__ h1b, float* __restrict__ a_s1,
    float* __restrict__ a_d1, int N)
{
    __shared__ float xs[32 * 128];   // per wave region w*1024, layout [k*8+nb]
    const int t  = threadIdx.x;
    const int n0 = blockIdx.x * 32;
    for (int i = t; i < 32 * 128; i += 256) {
        const int nb_l = i >> 7, k = i & 127;
        const int n = min(n0 + nb_l, N - 1);
        xs[(nb_l >> 3) * 1024 + k * 8 + (nb_l & 7)] = x[(size_t)n * IN_DIM + k];
    }
    __syncthreads();
    const int w = t >> 6, l = t & 63;
    const float* xw = xs + w * 1024;
    float4 acc[8];
    #pragma unroll
    for (int nb = 0; nb < 8; ++nb) acc[nb] = make_float4(0.f, 0.f, 0.f, 0.f);
    const float4* W1v = (const float4*)W1;   // W1[k*256 + l*4] = W1v[k*64 + l]
    #pragma unroll 4
    for (int k = 0; k < 128; ++k) {
        const float4 wa = W1v[k * 64 + l];
        const float4 xa = *(const float4*)&xw[k * 8];
        const float4 xb = *(const float4*)&xw[k * 8 + 4];
        const float xv[8] = {xa.x, xa.y, xa.z, xa.w, xb.x, xb.y, xb.z, xb.w};
        #pragma unroll
        for (int nb = 0; nb < 8; ++nb) {
            acc[nb].x += xv[nb] * wa.x;
            acc[nb].y += xv[nb] * wa.y;
            acc[nb].z += xv[nb] * wa.z;
            acc[nb].w += xv[nb] * wa.w;
        }
    }
    const float4 s4 = *(const float4*)&as1[l * 4];
    const float4 d4 = *(const float4*)&ad1[l * 4];
    #pragma unroll
    for (int nb = 0; nb < 8; ++nb) {
        const int n = n0 + w * 8 + nb;
        if (n >= N) break;
        ushort4 o;
        o.x = pk(acc[nb].x); o.y = pk(acc[nb].y);
        o.z = pk(acc[nb].z); o.w = pk(acc[nb].w);
        *(ushort4*)&h1b[(size_t)n * C1 + l * 4] = o;
        float vs = acc[nb].x * s4.x + acc[nb].y * s4.y + acc[nb].z * s4.z + acc[nb].w * s4.w;
        float vd = acc[nb].x * d4.x + acc[nb].y * d4.y + acc[nb].z * d4.z + acc[nb].w * d4.w;
        #pragma unroll
        for (int off = 1; off < 16; off <<= 1) {
            vs += __shfl_xor(vs, off, 64);
            vd += __shfl_xor(vd, off, 64);
        }
        if ((l & 15) == 0) {
            a_s1[n * HEADS + (l >> 4)] = vs;
            a_d1[n * HEADS + (l >> 4)] = vd;
        }
    }
}

// ================= CSR build =================
__global__ void deg_k(const int* __restrict__ ei, int E, int Etot,
                      int* __restrict__ rowptr)
{
    const int e = blockIdx.x * blockDim.x + threadIdx.x;
    if (e >= Etot) return;
    const int d = (e < E) ? ei[E + e] : e - E;
    atomicAdd(&rowptr[1 + d], 1);
}

__device__ __forceinline__ int blk_incl_scan(int v, int t) {
    __shared__ int wsum[4];
    const int lane = t & 63, wid = t >> 6;
    int s = v;
    #pragma unroll
    for (int off = 1; off < 64; off <<= 1) {
        const int u = __shfl_up(s, off, 64);
        if (lane >= off) s += u;
    }
    if (lane == 63) wsum[wid] = s;
    __syncthreads();
    int add = 0;
    #pragma unroll
    for (int k = 0; k < 4; ++k) if (k < wid) add += wsum[k];
    __syncthreads();
    return s + add;
}

__global__ __launch_bounds__(256) void scanA_k(const int* __restrict__ rowptr,
                                               int* __restrict__ psum, int N)
{
    const int t = threadIdx.x;
    const int i = blockIdx.x * 256 + t;
    int v = (i < N) ? rowptr[1 + i] : 0;
    #pragma unroll
    for (int off = 1; off < 64; off <<= 1) v += __shfl_xor(v, off, 64);
    __shared__ int ws[4];
    if ((t & 63) == 0) ws[t >> 6] = v;
    __syncthreads();
    if (t == 0) psum[blockIdx.x] = ws[0] + ws[1] + ws[2] + ws[3];
}

__global__ __launch_bounds__(256) void scanB_k(int* __restrict__ psum, int SC)
{
    const int t = threadIdx.x;
    const int v = (t < SC) ? psum[t] : 0;
    const int inc = blk_incl_scan(v, t);
    if (t < SC) psum[t] = inc - v;   // exclusive
}

__global__ __launch_bounds__(256) void scanC_k(int* __restrict__ rowptr,
                                               int* __restrict__ cursor,
                                               const int* __restrict__ psum, int N)
{
    const int t = threadIdx.x;
    const int i = blockIdx.x * 256 + t;
    const int v = (i < N) ? rowptr[1 + i] : 0;
    const int inc = blk_incl_scan(v, t);
    const int base = psum[blockIdx.x];
    if (i < N) {
        rowptr[1 + i] = base + inc;
        cursor[i]     = base + inc - v;
    }
}

__global__ void fill_k(const int* __restrict__ ei, int E, int Etot,
                       int* __restrict__ cursor, int* __restrict__ col,
                       int* __restrict__ row)
{
    const int e = blockIdx.x * blockDim.x + threadIdx.x;
    if (e >= Etot) return;
    int s, d;
    if (e < E) { s = ei[e]; d = ei[E + e]; } else { s = d = e - E; }
    const int pos = atomicAdd(&cursor[d], 1);
    col[pos] = s;
    row[pos] = d;
}

// ============ per-edge softmax weights, CSR order, interleaved [p*4+h] ======
__global__ void ew1_k(const int* __restrict__ col, const int* __restrict__ row,
                      const float* __restrict__ a_s1, const float* __restrict__ a_d1,
                      float* __restrict__ ew1, int Etot)
{
    const int p = blockIdx.x * blockDim.x + threadIdx.x;
    if (p >= Etot) return;
    const int s = col[p], d = row[p];
    const float4 sv = *(const float4*)&a_s1[s * 4];
    const float4 dv = *(const float4*)&a_d1[d * 4];
    float4 w;
    w.x = expc(lrelu(sv.x + dv.x));
    w.y = expc(lrelu(sv.y + dv.y));
    w.z = expc(lrelu(sv.z + dv.z));
    w.w = expc(lrelu(sv.w + dv.w));
    *(float4*)&ew1[(size_t)p * 4] = w;
}

__global__ void ew2_k(const int* __restrict__ col, const int* __restrict__ row,
                      const float* __restrict__ a_s2, const float* __restrict__ a_d2,
                      float* __restrict__ ew2, int Etot)
{
    const int p = blockIdx.x * blockDim.x + threadIdx.x;
    if (p >= Etot) return;
    ew2[p] = expc(lrelu(a_s2[col[p]] + a_d2[row[p]]));
}

// ====== Layer-1 aggregate: 1 wave/node, lane = 4 channels (ushort4 gather) ==
// block 256 = 4 waves = 4 nodes; head of lane = l>>4.
__global__ __launch_bounds__(256) void agg1_k(
    const int* __restrict__ rowptr, const int* __restrict__ col,
    const float* __restrict__ ew1, const unsigned short* __restrict__ h1b,
    const float* __restrict__ b1, unsigned short* __restrict__ hxb, int N)
{
    const int t = threadIdx.x, w = t >> 6, l = t & 63;
    const int n = blockIdx.x * 4 + w;
    if (n >= N) return;
    const int beg = rowptr[n], end = rowptr[n + 1];
    const int head = l >> 4;
    float a0 = 0.f, a1 = 0.f, a2 = 0.f, a3 = 0.f, wsum = 0.f;
    for (int t0 = beg; t0 < end; t0 += 64) {
        const int m = min(64, end - t0);
        const int p = t0 + l;
        const int scol = (p < end) ? col[p] : 0;
        for (int j0 = 0; j0 < m; j0 += 16) {
            const int pe = t0 + j0 + (l & 15);                 // 16 edges staged
            const float wst = (pe < end) ? ew1[(size_t)pe * 4 + head] : 0.f;
            const int mm = min(16, m - j0);
            #pragma unroll 8
            for (int jj = 0; jj < mm; ++jj) {
                const int   su = __shfl(scol, j0 + jj, 64);
                const float wu = __shfl(wst, (l & 48) + jj, 64);
                const ushort4 hv = *(const ushort4*)(h1b + (size_t)su * C1 + 4 * l);
                a0 = fmaf(bfu(hv.x), wu, a0);
                a1 = fmaf(bfu(hv.y), wu, a1);
                a2 = fmaf(bfu(hv.z), wu, a2);
                a3 = fmaf(bfu(hv.w), wu, a3);
                wsum += wu;
            }
        }
    }
    const float4 bb = *(const float4*)&b1[4 * l];
    const float inv = 1.f / (wsum + 1e-16f);
    ushort4 o;
    o.x = pk(elu1(a0 * inv + bb.x));
    o.y = pk(elu1(a1 * inv + bb.y));
    o.z = pk(elu1(a2 * inv + bb.z));
    o.w = pk(elu1(a3 * inv + bb.w));
    *(ushort4*)&hxb[(size_t)n * C1 + 4 * l] = o;
}

// ================= Layer-2 GEMV: h2 = h @ W2 (bf16 table), logits ============
__global__ __launch_bounds__(256) void gemm2_k(
    const unsigned short* __restrict__ hxb, const float* __restrict__ W2,
    const float* __restrict__ as2, const float* __restrict__ ad2,
    unsigned short* __restrict__ h2b, float* __restrict__ a_s2,
    float* __restrict__ a_d2, int N)
{
    __shared__ float hs[32 * 256];   // 32 KB; wave region w*2048, [k*8+nb]
    const int t = threadIdx.x;
    const int n0 = blockIdx.x * 32;
    for (int i = t; i < 32 * 256; i += 256) {
        const int nb_l = i >> 8, k = i & 255;
        const int n = min(n0 + nb_l, N - 1);
        hs[(nb_l >> 3) * 2048 + k * 8 + (nb_l & 7)] = bfu(hxb[(size_t)n * C1 + k]);
    }
    __syncthreads();
    const int w = t >> 6, l = t & 63;
    const float* hw = hs + w * 2048;
    float acc[8] = {0.f, 0.f, 0.f, 0.f, 0.f, 0.f, 0.f, 0.f};
    #pragma unroll 4
    for (int k = 0; k < 256; ++k) {
        const float wv = W2[k * OUT_DIM + l];
        const float4 xa = *(const float4*)&hw[k * 8];
        const float4 xb = *(const float4*)&hw[k * 8 + 4];
        acc[0] += xa.x * wv; acc[1] += xa.y * wv;
        acc[2] += xa.z * wv; acc[3] += xa.w * wv;
        acc[4] += xb.x * wv; acc[5] += xb.y * wv;
        acc[6] += xb.z * wv; acc[7] += xb.w * wv;
    }
    const float sv2 = as2[l], dv2 = ad2[l];
    #pragma unroll
    for (int nb = 0; nb < 8; ++nb) {
        const int n = n0 + w * 8 + nb;
        if (n >= N) break;
        h2b[(size_t)n * OUT_DIM + l] = pk(acc[nb]);
        float vs = acc[nb] * sv2, vd = acc[nb] * dv2;
        #pragma unroll
        for (int off = 1; off < 64; off <<= 1) {
            vs += __shfl_xor(vs, off, 64);
            vd += __shfl_xor(vd, off, 64);
        }
        if (l == 0) { a_s2[n] = vs; a_d2[n] = vd; }
    }
}

// ====== Layer-2 aggregate: 1 wave/node, 2 edges/step (lane = 2 ch) ======
__global__ __launch_bounds__(256) void agg2_k(
    const int* __restrict__ rowptr, const int* __restrict__ col,
    const float* __restrict__ ew2, const unsigned short* __restrict__ h2b,
    const float* __restrict__ b2, float* __restrict__ zout, int N)
{
    const int t = threadIdx.x, w = t >> 6, l = t & 63;
    const int n = blockIdx.x * 4 + w;
    if (n >= N) return;
    const int beg = rowptr[n], end = rowptr[n + 1];
    const int half = l >> 5, c2 = l & 31;     // lane owns ch 2*c2, 2*c2+1
    float a0 = 0.f, a1 = 0.f, wsum = 0.f;
    for (int t0 = beg; t0 < end; t0 += 64) {
        const int m = min(64, end - t0);
        const int p = t0 + l;
        const int   scol = (p < end) ? col[p] : 0;
        const float wv   = (p < end) ? ew2[p] : 0.f;
        const int pairs = (m + 1) >> 1;
        #pragma unroll 4
        for (int j = 0; j < pairs; ++j) {
            const int e = 2 * j + half;               // staged lane idx (<64)
            const int   su = __shfl(scol, e, 64);
            const float wu = __shfl(wv, e, 64);
            const unsigned int hv =
                *(const unsigned int*)(h2b + (size_t)su * OUT_DIM + 2 * c2);
            a0 = fmaf(bfu(hv & 0xffffu), wu, a0);
            a1 = fmaf(bfu(hv >> 16), wu, a1);
            wsum += wu;
        }
    }
    a0   += __shfl_xor(a0, 32, 64);
    a1   += __shfl_xor(a1, 32, 64);
    wsum += __shfl_xor(wsum, 32, 64);
    const float inv = 1.f / (wsum + 1e-16f);
    float z0 = a0 * inv + b2[2 * c2];
    float z1 = a1 * inv + b2[2 * c2 + 1];
    float sq = z0 * z0 + z1 * z1;
    #pragma unroll
    for (int off = 1; off < 32; off <<= 1) sq += __shfl_xor(sq, off, 64);
    const float rn = 1.f / fmaxf(sqrtf(sq), 1e-12f);
    if (l < 32) {
        float2 o; o.x = z0 * rn; o.y = z1 * rn;
        *(float2*)&zout[(size_t)n * OUT_DIM + 2 * c2] = o;
    }
}

// ================= Decoder: x_hat = elu(z@dW1+db1)@dW2+db2 =================
__global__ __launch_bounds__(256) void dec_k(
    const float* __restrict__ z,
    const float* __restrict__ dW1, const float* __restrict__ db1,
    const float* __restrict__ dW2, const float* __restrict__ db2,
    float* __restrict__ xhat, int N)
{
    __shared__ float zs[32 * 64];
    __shared__ float ts[32 * 64];
    const int t = threadIdx.x;
    const int n0 = blockIdx.x * 32;
    for (int i = t; i < 32 * 64; i += 256) {
        const int nb_l = i >> 6, k = i & 63;
        const int n = min(n0 + nb_l, N - 1);
        zs[(nb_l >> 3) * 512 + k * 8 + (nb_l & 7)] = z[(size_t)n * OUT_DIM + k];
    }
    __syncthreads();
    const int w = t >> 6, l = t & 63;
    const float* zw = zs + w * 512;
    float* tw = ts + w * 512;
    float acc[8] = {0.f, 0.f, 0.f, 0.f, 0.f, 0.f, 0.f, 0.f};
    #pragma unroll 4
    for (int k = 0; k < 64; ++k) {
        const float wv = dW1[k * HID + l];
        const float4 xa = *(const float4*)&zw[k * 8];
        const float4 xb = *(const float4*)&zw[k * 8 + 4];
        acc[0] += xa.x * wv; acc[1] += xa.y * wv;
        acc[2] += xa.z * wv; acc[3] += xa.w * wv;
        acc[4] += xb.x * wv; acc[5] += xb.y * wv;
        acc[6] += xb.z * wv; acc[7] += xb.w * wv;
    }
    const float bb = db1[l];
    #pragma unroll
    for (int nb = 0; nb < 8; ++nb) tw[l * 8 + nb] = elu1(acc[nb] + bb);
    __syncthreads();
    float a0[8] = {0.f, 0.f, 0.f, 0.f, 0.f, 0.f, 0.f, 0.f};
    float a1[8] = {0.f, 0.f, 0.f, 0.f, 0.f, 0.f, 0.f, 0.f};
    #pragma unroll 2
    for (int k = 0; k < 64; ++k) {
        const float w0 = dW2[k * IN_DIM + l];
        const float w1 = dW2[k * IN_DIM + 64 + l];
        const float4 xa = *(const float4*)&tw[k * 8];
        const float4 xb = *(const float4*)&tw[k * 8 + 4];
        const float xv[8] = {xa.x, xa.y, xa.z, xa.w, xb.x, xb.y, xb.z, xb.w};
        #pragma unroll
        for (int nb = 0; nb < 8; ++nb) {
            a0[nb] += xv[nb] * w0;
            a1[nb] += xv[nb] * w1;
        }
    }
    const float bb0 = db2[l], bb1 = db2[64 + l];
    #pragma unroll
    for (int nb = 0; nb < 8; ++nb) {
        const int n = n0 + w * 8 + nb;
        if (n >= N) break;
        xhat[(size_t)n * IN_DIM + l]      = a0[nb] + bb0;
        xhat[(size_t)n * IN_DIM + 64 + l] = a1[nb] + bb1;
    }
}

extern "C" void kernel_launch(void* const* d_in, const int* in_sizes, int n_in,
                              void* d_out, int out_size, void* d_ws, size_t ws_size,
                              hipStream_t stream)
{
    const float* x   = (const float*)d_in[0];
    const int*   ei  = (const int*)d_in[1];
    const float* W1  = (const float*)d_in[2];
    const float* as1 = (const float*)d_in[3];
    const float* ad1 = (const float*)d_in[4];
    const float* b1  = (const float*)d_in[5];
    const float* W2  = (const float*)d_in[6];
    const float* as2 = (const float*)d_in[7];
    const float* ad2 = (const float*)d_in[8];
    const float* b2  = (const float*)d_in[9];
    const float* dW1 = (const float*)d_in[10];
    const float* db1 = (const float*)d_in[11];
    const float* dW2 = (const float*)d_in[12];
    const float* db2 = (const float*)d_in[13];

    const int N    = in_sizes[0] / IN_DIM;
    const int E    = in_sizes[1] / 2;
    const int Etot = E + N;

    float* ws = (float*)d_ws;
    unsigned short* hxb = (unsigned short*)ws;   // N*256 bf16 (in N*256 f32 slot)
    float* a_s1 = ws   + (size_t)N * C1;         // N*4
    float* a_d1 = a_s1 + (size_t)N * HEADS;      // N*4
    float* a_s2 = a_d1 + (size_t)N * HEADS;      // N
    float* a_d2 = a_s2 + (size_t)N;              // N
    float* ew1  = a_d2 + (size_t)N;              // Etot*4 (interleaved [p*4+h])
    float* ew2  = ew1  + (size_t)Etot * HEADS;   // Etot
    unsigned short* h1b = (unsigned short*)(ew2 + (size_t)Etot);  // N*256 bf16
    unsigned short* h2b = h1b + (size_t)N * C1;                   // N*64 bf16
    int* rowptr = (int*)(h2b + (size_t)N * OUT_DIM);              // N+1
    int* cursor = rowptr + (N + 1);              // N
    int* col    = cursor + N;                    // Etot
    int* row    = col    + Etot;                 // Etot
    int* psum   = row    + Etot;                 // 256

    const size_t needed = ((size_t)N * 428 + 257 + (size_t)Etot * 7) * 4;
    if (ws_size < needed) return;  // loud failure signature (absmax ~0.543)

    hipMemsetAsync(rowptr, 0, (size_t)(N + 1) * sizeof(int), stream);

    const int nblk = (N + 31) / 32;
    const int eblk = (Etot + 255) / 256;
    const int SC   = (N + 255) / 256;            // <=256 chunks (N=50k -> 196)
    gemm1_k<<<nblk, 256, 0, stream>>>(x, W1, as1, ad1, h1b, a_s1, a_d1, N);
    deg_k  <<<eblk, 256, 0, stream>>>(ei, E, Etot, rowptr);
    scanA_k<<<SC, 256, 0, stream>>>(rowptr, psum, N);
    scanB_k<<<1, 256, 0, stream>>>(psum, SC);
    scanC_k<<<SC, 256, 0, stream>>>(rowptr, cursor, psum, N);
    fill_k <<<eblk, 256, 0, stream>>>(ei, E, Etot, cursor, col, row);
    ew1_k  <<<eblk, 256, 0, stream>>>(col, row, a_s1, a_d1, ew1, Etot);
    agg1_k <<<(N + 3) / 4, 256, 0, stream>>>(rowptr, col, ew1, h1b, b1, hxb, N);
    gemm2_k<<<nblk, 256, 0, stream>>>(hxb, W2, as2, ad2, h2b, a_s2, a_d2, N);
    ew2_k  <<<eblk, 256, 0, stream>>>(col, row, a_s2, a_d2, ew2, Etot);
    agg2_k <<<(N + 3) / 4, 256, 0, stream>>>(rowptr, col, ew2, h2b, b2,
                                             (float*)d_out, N);
    dec_k  <<<nblk, 256, 0, stream>>>((const float*)d_out, dW1, db1, dW2, db2,
                                      (float*)d_out + (size_t)N * OUT_DIM, N);
}

// Round 9
// 381.108 us; speedup vs baseline: 1.6572x; 1.1579x over previous
//
#include <hip/hip_runtime.h>
#include <hip/hip_bf16.h>

// GAT-GAE forward: 2x GATConv + normalize + MLP decoder. fp32 I/O, int32 edges.
// Round 9: (a) agg1/agg2 batch-load arrays force 8 gathers in flight (R8's
// VGPR=20 showed the compiler serialized them); (b) gemm1/gemm2 -> MFMA
// 16x16x32 bf16 with fragment-ordered weight tables (W1f/W2f) prepacked per
// launch, LDS-transposed epilogues, fused logits.
//
// Workspace: hxb[N*256 f32 slot] | a_s1[4N] | a_d1[4N] | a_s2[N] | a_d2[N] |
//   ew1[4*Etot] | ew2[Etot] | h1b[N*256]u16 | h2b[N*64]u16 |
//   rowptr[N+1] | cursor[N] | col[Etot] | row[Etot] | psum[256] |
//   W1f[32768]u16 | W2f[16384]u16

#define IN_DIM   128
#define C1       256   // HEADS*HID
#define HEADS    4
#define HID      64
#define OUT_DIM  64

typedef __attribute__((ext_vector_type(8))) short short8;
typedef __attribute__((ext_vector_type(4))) float f32x4;

__device__ __forceinline__ float lrelu(float x) { return x > 0.f ? x : 0.2f * x; }
__device__ __forceinline__ float elu1(float x)  { return x > 0.f ? x : (__expf(x) - 1.f); }
__device__ __forceinline__ float expc(float x)  { return __expf(fminf(x, 60.f)); }
__device__ __forceinline__ float bfu(unsigned int u) {
    union { unsigned int i; float f; } c; c.i = u << 16; return c.f;
}
__device__ __forceinline__ unsigned short pk(float f) {
    union { float f; unsigned int i; } c; c.f = f;
    return (unsigned short)((c.i + 0x7fffu + ((c.i >> 16) & 1u)) >> 16);
}

// ============ weight prepack: B-fragment order for 16x16x32 bf16 ============
// W1 [128][256] fp32 -> W1f[((nt*4+kc)*64 + lane)*8 + j] =
//   bf16(W1[(kc*32 + (lane>>4)*8 + j)*256 + nt*16 + (lane&15)])
__global__ __launch_bounds__(256) void w1f_k(const float* __restrict__ W1,
                                             unsigned short* __restrict__ W1f)
{
    const int idx = blockIdx.x * 256 + threadIdx.x;   // 4096 lane-entries
    if (idx >= 64 * 64) return;
    const int lane = idx & 63, e = idx >> 6;
    const int nt = e >> 2, kc = e & 3, q = lane >> 4, c = lane & 15;
    unsigned short tmp[8];
    #pragma unroll
    for (int j = 0; j < 8; ++j)
        tmp[j] = pk(W1[(kc * 32 + q * 8 + j) * 256 + nt * 16 + c]);
    ushort4* dst = (ushort4*)(W1f + (size_t)idx * 8);
    dst[0] = make_ushort4(tmp[0], tmp[1], tmp[2], tmp[3]);
    dst[1] = make_ushort4(tmp[4], tmp[5], tmp[6], tmp[7]);
}

// W2 [256][64] fp32 -> W2f[((nt*8+kc)*64 + lane)*8 + j]
__global__ __launch_bounds__(256) void w2f_k(const float* __restrict__ W2,
                                             unsigned short* __restrict__ W2f)
{
    const int idx = blockIdx.x * 256 + threadIdx.x;   // 2048 lane-entries
    if (idx >= 32 * 64) return;
    const int lane = idx & 63, e = idx >> 6;
    const int nt = e >> 3, kc = e & 7, q = lane >> 4, c = lane & 15;
    unsigned short tmp[8];
    #pragma unroll
    for (int j = 0; j < 8; ++j)
        tmp[j] = pk(W2[(kc * 32 + q * 8 + j) * 64 + nt * 16 + c]);
    ushort4* dst = (ushort4*)(W2f + (size_t)idx * 8);
    dst[0] = make_ushort4(tmp[0], tmp[1], tmp[2], tmp[3]);
    dst[1] = make_ushort4(tmp[4], tmp[5], tmp[6], tmp[7]);
}

// ============ Layer-1 GEMM (MFMA): h1 = x @ W1 (bf16 table) + logits ========
// block 256 = 4 waves; M-tile 64 (wave w -> rows 16w..16w+15), N=256, K=128.
__global__ __launch_bounds__(256) void gemm1_k(
    const float* __restrict__ x, const unsigned short* __restrict__ W1f,
    const float* __restrict__ as1, const float* __restrict__ ad1,
    unsigned short* __restrict__ h1b, float* __restrict__ a_s1,
    float* __restrict__ a_d1, int N)
{
    __shared__ short lds[64 * 264];   // stage: [row][136]; epilogue: [row][264]
    const int t = threadIdx.x, w = t >> 6, l = t & 63;
    const int q = l >> 4, c = l & 15;
    const int n0 = blockIdx.x * 64;
    // stage x (fp32 -> bf16) into LDS rows, stride 136
    for (int i = t; i < 64 * 32; i += 256) {
        const int r = i >> 5, k4 = (i & 31) * 4;
        const int rn = min(n0 + r, N - 1);
        const float4 v = *(const float4*)&x[(size_t)rn * IN_DIM + k4];
        *(ushort4*)&lds[r * 136 + k4] =
            make_ushort4(pk(v.x), pk(v.y), pk(v.z), pk(v.w));
    }
    __syncthreads();
    short8 afr[4];
    const int arow = 16 * w + c;
    #pragma unroll
    for (int kc = 0; kc < 4; ++kc)
        afr[kc] = *(const short8*)&lds[arow * 136 + kc * 32 + q * 8];
    f32x4 acc[16];
    #pragma unroll
    for (int nt = 0; nt < 16; ++nt) acc[nt] = (f32x4){0.f, 0.f, 0.f, 0.f};
    #pragma unroll
    for (int nt = 0; nt < 16; ++nt) {
        #pragma unroll
        for (int kc = 0; kc < 4; ++kc) {
            const short8 bfr =
                *(const short8*)(W1f + ((size_t)(nt * 4 + kc) * 64 + l) * 8);
            acc[nt] = __builtin_amdgcn_mfma_f32_16x16x32_bf16(afr[kc], bfr,
                                                              acc[nt], 0, 0, 0);
        }
    }
    // fused logits: head h covers ntiles 4h..4h+3; rows q*4+r; cols nt*16+c
    #pragma unroll
    for (int h = 0; h < 4; ++h) {
        float vsr[4] = {0.f, 0.f, 0.f, 0.f}, vdr[4] = {0.f, 0.f, 0.f, 0.f};
        #pragma unroll
        for (int n4 = 0; n4 < 4; ++n4) {
            const int nt = h * 4 + n4;
            const float sa = as1[nt * 16 + c], da = ad1[nt * 16 + c];
            #pragma unroll
            for (int r = 0; r < 4; ++r) {
                vsr[r] += acc[nt][r] * sa;
                vdr[r] += acc[nt][r] * da;
            }
        }
        #pragma unroll
        for (int r = 0; r < 4; ++r) {
            #pragma unroll
            for (int off = 1; off < 16; off <<= 1) {
                vsr[r] += __shfl_xor(vsr[r], off, 64);
                vdr[r] += __shfl_xor(vdr[r], off, 64);
            }
            const int node = n0 + 16 * w + q * 4 + r;
            if (c == 0 && node < N) {
                a_s1[node * 4 + h] = vsr[r];
                a_d1[node * 4 + h] = vdr[r];
            }
        }
    }
    __syncthreads();
    #pragma unroll
    for (int nt = 0; nt < 16; ++nt)
        #pragma unroll
        for (int r = 0; r < 4; ++r)
            lds[(16 * w + q * 4 + r) * 264 + nt * 16 + c] = (short)pk(acc[nt][r]);
    __syncthreads();
    for (int i = t; i < 64 * 32; i += 256) {
        const int r = i >> 5, ch = (i & 31) * 8;
        const int node = n0 + r;
        if (node < N)
            *(short8*)&h1b[(size_t)node * C1 + ch] =
                *(const short8*)&lds[r * 264 + ch];
    }
}

// ================= CSR build =================
__global__ void deg_k(const int* __restrict__ ei, int E, int Etot,
                      int* __restrict__ rowptr)
{
    const int e = blockIdx.x * blockDim.x + threadIdx.x;
    if (e >= Etot) return;
    const int d = (e < E) ? ei[E + e] : e - E;
    atomicAdd(&rowptr[1 + d], 1);
}

__device__ __forceinline__ int blk_incl_scan(int v, int t) {
    __shared__ int wsum[4];
    const int lane = t & 63, wid = t >> 6;
    int s = v;
    #pragma unroll
    for (int off = 1; off < 64; off <<= 1) {
        const int u = __shfl_up(s, off, 64);
        if (lane >= off) s += u;
    }
    if (lane == 63) wsum[wid] = s;
    __syncthreads();
    int add = 0;
    #pragma unroll
    for (int k = 0; k < 4; ++k) if (k < wid) add += wsum[k];
    __syncthreads();
    return s + add;
}

__global__ __launch_bounds__(256) void scanA_k(const int* __restrict__ rowptr,
                                               int* __restrict__ psum, int N)
{
    const int t = threadIdx.x;
    const int i = blockIdx.x * 256 + t;
    int v = (i < N) ? rowptr[1 + i] : 0;
    #pragma unroll
    for (int off = 1; off < 64; off <<= 1) v += __shfl_xor(v, off, 64);
    __shared__ int ws[4];
    if ((t & 63) == 0) ws[t >> 6] = v;
    __syncthreads();
    if (t == 0) psum[blockIdx.x] = ws[0] + ws[1] + ws[2] + ws[3];
}

__global__ __launch_bounds__(256) void scanB_k(int* __restrict__ psum, int SC)
{
    const int t = threadIdx.x;
    const int v = (t < SC) ? psum[t] : 0;
    const int inc = blk_incl_scan(v, t);
    if (t < SC) psum[t] = inc - v;   // exclusive
}

__global__ __launch_bounds__(256) void scanC_k(int* __restrict__ rowptr,
                                               int* __restrict__ cursor,
                                               const int* __restrict__ psum, int N)
{
    const int t = threadIdx.x;
    const int i = blockIdx.x * 256 + t;
    const int v = (i < N) ? rowptr[1 + i] : 0;
    const int inc = blk_incl_scan(v, t);
    const int base = psum[blockIdx.x];
    if (i < N) {
        rowptr[1 + i] = base + inc;
        cursor[i]     = base + inc - v;
    }
}

__global__ void fill_k(const int* __restrict__ ei, int E, int Etot,
                       int* __restrict__ cursor, int* __restrict__ col,
                       int* __restrict__ row)
{
    const int e = blockIdx.x * blockDim.x + threadIdx.x;
    if (e >= Etot) return;
    int s, d;
    if (e < E) { s = ei[e]; d = ei[E + e]; } else { s = d = e - E; }
    const int pos = atomicAdd(&cursor[d], 1);
    col[pos] = s;
    row[pos] = d;
}

// ============ per-edge softmax weights, CSR order, interleaved [p*4+h] ======
__global__ void ew1_k(const int* __restrict__ col, const int* __restrict__ row,
                      const float* __restrict__ a_s1, const float* __restrict__ a_d1,
                      float* __restrict__ ew1, int Etot)
{
    const int p = blockIdx.x * blockDim.x + threadIdx.x;
    if (p >= Etot) return;
    const int s = col[p], d = row[p];
    const float4 sv = *(const float4*)&a_s1[s * 4];
    const float4 dv = *(const float4*)&a_d1[d * 4];
    float4 w;
    w.x = expc(lrelu(sv.x + dv.x));
    w.y = expc(lrelu(sv.y + dv.y));
    w.z = expc(lrelu(sv.z + dv.z));
    w.w = expc(lrelu(sv.w + dv.w));
    *(float4*)&ew1[(size_t)p * 4] = w;
}

__global__ void ew2_k(const int* __restrict__ col, const int* __restrict__ row,
                      const float* __restrict__ a_s2, const float* __restrict__ a_d2,
                      float* __restrict__ ew2, int Etot)
{
    const int p = blockIdx.x * blockDim.x + threadIdx.x;
    if (p >= Etot) return;
    ew2[p] = expc(lrelu(a_s2[col[p]] + a_d2[row[p]]));
}

// ====== Layer-1 aggregate: 1 wave/node, lane = 4 ch; batched 8-deep gathers ==
__global__ __launch_bounds__(256) void agg1_k(
    const int* __restrict__ rowptr, const int* __restrict__ col,
    const float* __restrict__ ew1, const unsigned short* __restrict__ h1b,
    const float* __restrict__ b1, unsigned short* __restrict__ hxb, int N)
{
    const int t = threadIdx.x, w = t >> 6, l = t & 63;
    const int n = blockIdx.x * 4 + w;
    if (n >= N) return;
    const int beg = rowptr[n], end = rowptr[n + 1];
    const int head = l >> 4;
    float a0 = 0.f, a1 = 0.f, a2 = 0.f, a3 = 0.f, wsum = 0.f;
    for (int t0 = beg; t0 < end; t0 += 16) {
        const int m = min(16, end - t0);
        const int pe = t0 + (l & 15);
        const int   scol = (pe < end) ? col[pe] : 0;
        const float wst  = (pe < end) ? ew1[(size_t)pe * 4 + head] : 0.f;
        for (int j0 = 0; j0 < m; j0 += 8) {
            ushort4 hv[8]; float wu[8];
            #pragma unroll
            for (int u = 0; u < 8; ++u) {                 // 8 independent loads
                const int su = __shfl(scol, j0 + u, 64);
                wu[u] = __shfl(wst, (l & 48) + j0 + u, 64);
                hv[u] = *(const ushort4*)(h1b + (size_t)su * C1 + 4 * l);
            }
            #pragma unroll
            for (int u = 0; u < 8; ++u) {
                a0 = fmaf(bfu(hv[u].x), wu[u], a0);
                a1 = fmaf(bfu(hv[u].y), wu[u], a1);
                a2 = fmaf(bfu(hv[u].z), wu[u], a2);
                a3 = fmaf(bfu(hv[u].w), wu[u], a3);
                wsum += wu[u];
            }
        }
    }
    const float4 bb = *(const float4*)&b1[4 * l];
    const float inv = 1.f / (wsum + 1e-16f);
    ushort4 o;
    o.x = pk(elu1(a0 * inv + bb.x));
    o.y = pk(elu1(a1 * inv + bb.y));
    o.z = pk(elu1(a2 * inv + bb.z));
    o.w = pk(elu1(a3 * inv + bb.w));
    *(ushort4*)&hxb[(size_t)n * C1 + 4 * l] = o;
}

// ============ Layer-2 GEMM (MFMA): h2 = h @ W2 (bf16) + logits ==============
// block 256 = 4 waves; M-tile 64, N=64 (4 ntiles), K=256 (8 kc).
__global__ __launch_bounds__(256) void gemm2_k(
    const unsigned short* __restrict__ hxb, const unsigned short* __restrict__ W2f,
    const float* __restrict__ as2, const float* __restrict__ ad2,
    unsigned short* __restrict__ h2b, float* __restrict__ a_s2,
    float* __restrict__ a_d2, int N)
{
    __shared__ short lds[64 * 264];   // stage: [row][264] (K=256+pad8)
    const int t = threadIdx.x, w = t >> 6, l = t & 63;
    const int q = l >> 4, c = l & 15;
    const int n0 = blockIdx.x * 64;
    for (int i = t; i < 64 * 32; i += 256) {
        const int r = i >> 5, ch = (i & 31) * 8;
        const int rn = min(n0 + r, N - 1);
        *(short8*)&lds[r * 264 + ch] =
            *(const short8*)&hxb[(size_t)rn * C1 + ch];
    }
    __syncthreads();
    short8 afr[8];
    const int arow = 16 * w + c;
    #pragma unroll
    for (int kc = 0; kc < 8; ++kc)
        afr[kc] = *(const short8*)&lds[arow * 264 + kc * 32 + q * 8];
    f32x4 acc[4];
    #pragma unroll
    for (int nt = 0; nt < 4; ++nt) acc[nt] = (f32x4){0.f, 0.f, 0.f, 0.f};
    #pragma unroll
    for (int nt = 0; nt < 4; ++nt) {
        #pragma unroll
        for (int kc = 0; kc < 8; ++kc) {
            const short8 bfr =
                *(const short8*)(W2f + ((size_t)(nt * 8 + kc) * 64 + l) * 8);
            acc[nt] = __builtin_amdgcn_mfma_f32_16x16x32_bf16(afr[kc], bfr,
                                                              acc[nt], 0, 0, 0);
        }
    }
    // logits (single head over all 64 cols)
    {
        float vsr[4] = {0.f, 0.f, 0.f, 0.f}, vdr[4] = {0.f, 0.f, 0.f, 0.f};
        #pragma unroll
        for (int nt = 0; nt < 4; ++nt) {
            const float sa = as2[nt * 16 + c], da = ad2[nt * 16 + c];
            #pragma unroll
            for (int r = 0; r < 4; ++r) {
                vsr[r] += acc[nt][r] * sa;
                vdr[r] += acc[nt][r] * da;
            }
        }
        #pragma unroll
        for (int r = 0; r < 4; ++r) {
            #pragma unroll
            for (int off = 1; off < 16; off <<= 1) {
                vsr[r] += __shfl_xor(vsr[r], off, 64);
                vdr[r] += __shfl_xor(vdr[r], off, 64);
            }
            const int node = n0 + 16 * w + q * 4 + r;
            if (c == 0 && node < N) {
                a_s2[node] = vsr[r];
                a_d2[node] = vdr[r];
            }
        }
    }
    __syncthreads();
    #pragma unroll
    for (int nt = 0; nt < 4; ++nt)
        #pragma unroll
        for (int r = 0; r < 4; ++r)
            lds[(16 * w + q * 4 + r) * 72 + nt * 16 + c] = (short)pk(acc[nt][r]);
    __syncthreads();
    for (int i = t; i < 64 * 8; i += 256) {
        const int r = i >> 3, ch = (i & 7) * 8;
        const int node = n0 + r;
        if (node < N)
            *(short8*)&h2b[(size_t)node * OUT_DIM + ch] =
                *(const short8*)&lds[r * 72 + ch];
    }
}

// ====== Layer-2 aggregate: 1 wave/node, lane = 2 ch; batched 8-deep ======
__global__ __launch_bounds__(256) void agg2_k(
    const int* __restrict__ rowptr, const int* __restrict__ col,
    const float* __restrict__ ew2, const unsigned short* __restrict__ h2b,
    const float* __restrict__ b2, float* __restrict__ zout, int N)
{
    const int t = threadIdx.x, w = t >> 6, l = t & 63;
    const int n = blockIdx.x * 4 + w;
    if (n >= N) return;
    const int beg = rowptr[n], end = rowptr[n + 1];
    const int half = l >> 5, c2 = l & 31;     // lane owns ch 2*c2, 2*c2+1
    float a0 = 0.f, a1 = 0.f, wsum = 0.f;
    for (int t0 = beg; t0 < end; t0 += 64) {
        const int m = min(64, end - t0);
        const int p = t0 + l;
        const int   scol = (p < end) ? col[p] : 0;
        const float wv   = (p < end) ? ew2[p] : 0.f;
        const int pairs = (m + 1) >> 1;
        for (int j0 = 0; j0 < pairs; j0 += 8) {
            unsigned int hv[8]; float wu[8];
            #pragma unroll
            for (int u = 0; u < 8; ++u) {
                const int e = 2 * (j0 + u) + half;        // <= 63 always
                const int su = __shfl(scol, e, 64);
                wu[u] = __shfl(wv, e, 64);
                hv[u] = *(const unsigned int*)(h2b + (size_t)su * OUT_DIM + 2 * c2);
            }
            #pragma unroll
            for (int u = 0; u < 8; ++u) {
                a0 = fmaf(bfu(hv[u] & 0xffffu), wu[u], a0);
                a1 = fmaf(bfu(hv[u] >> 16), wu[u], a1);
                wsum += wu[u];
            }
        }
    }
    a0   += __shfl_xor(a0, 32, 64);
    a1   += __shfl_xor(a1, 32, 64);
    wsum += __shfl_xor(wsum, 32, 64);
    const float inv = 1.f / (wsum + 1e-16f);
    float z0 = a0 * inv + b2[2 * c2];
    float z1 = a1 * inv + b2[2 * c2 + 1];
    float sq = z0 * z0 + z1 * z1;
    #pragma unroll
    for (int off = 1; off < 32; off <<= 1) sq += __shfl_xor(sq, off, 64);
    const float rn = 1.f / fmaxf(sqrtf(sq), 1e-12f);
    if (l < 32) {
        float2 o; o.x = z0 * rn; o.y = z1 * rn;
        *(float2*)&zout[(size_t)n * OUT_DIM + 2 * c2] = o;
    }
}

// ================= Decoder: x_hat = elu(z@dW1+db1)@dW2+db2 =================
__global__ __launch_bounds__(256) void dec_k(
    const float* __restrict__ z,
    const float* __restrict__ dW1, const float* __restrict__ db1,
    const float* __restrict__ dW2, const float* __restrict__ db2,
    float* __restrict__ xhat, int N)
{
    __shared__ float zs[32 * 64];
    __shared__ float ts[32 * 64];
    const int t = threadIdx.x;
    const int n0 = blockIdx.x * 32;
    for (int i = t; i < 32 * 64; i += 256) {
        const int nb_l = i >> 6, k = i & 63;
        const int n = min(n0 + nb_l, N - 1);
        zs[(nb_l >> 3) * 512 + k * 8 + (nb_l & 7)] = z[(size_t)n * OUT_DIM + k];
    }
    __syncthreads();
    const int w = t >> 6, l = t & 63;
    const float* zw = zs + w * 512;
    float* tw = ts + w * 512;
    float acc[8] = {0.f, 0.f, 0.f, 0.f, 0.f, 0.f, 0.f, 0.f};
    #pragma unroll 4
    for (int k = 0; k < 64; ++k) {
        const float wv = dW1[k * HID + l];
        const float4 xa = *(const float4*)&zw[k * 8];
        const float4 xb = *(const float4*)&zw[k * 8 + 4];
        acc[0] += xa.x * wv; acc[1] += xa.y * wv;
        acc[2] += xa.z * wv; acc[3] += xa.w * wv;
        acc[4] += xb.x * wv; acc[5] += xb.y * wv;
        acc[6] += xb.z * wv; acc[7] += xb.w * wv;
    }
    const float bb = db1[l];
    #pragma unroll
    for (int nb = 0; nb < 8; ++nb) tw[l * 8 + nb] = elu1(acc[nb] + bb);
    __syncthreads();
    float a0[8] = {0.f, 0.f, 0.f, 0.f, 0.f, 0.f, 0.f, 0.f};
    float a1[8] = {0.f, 0.f, 0.f, 0.f, 0.f, 0.f, 0.f, 0.f};
    #pragma unroll 2
    for (int k = 0; k < 64; ++k) {
        const float w0 = dW2[k * IN_DIM + l];
        const float w1 = dW2[k * IN_DIM + 64 + l];
        const float4 xa = *(const float4*)&tw[k * 8];
        const float4 xb = *(const float4*)&tw[k * 8 + 4];
        const float xv[8] = {xa.x, xa.y, xa.z, xa.w, xb.x, xb.y, xb.z, xb.w};
        #pragma unroll
        for (int nb = 0; nb < 8; ++nb) {
            a0[nb] += xv[nb] * w0;
            a1[nb] += xv[nb] * w1;
        }
    }
    const float bb0 = db2[l], bb1 = db2[64 + l];
    #pragma unroll
    for (int nb = 0; nb < 8; ++nb) {
        const int n = n0 + w * 8 + nb;
        if (n >= N) break;
        xhat[(size_t)n * IN_DIM + l]      = a0[nb] + bb0;
        xhat[(size_t)n * IN_DIM + 64 + l] = a1[nb] + bb1;
    }
}

extern "C" void kernel_launch(void* const* d_in, const int* in_sizes, int n_in,
                              void* d_out, int out_size, void* d_ws, size_t ws_size,
                              hipStream_t stream)
{
    const float* x   = (const float*)d_in[0];
    const int*   ei  = (const int*)d_in[1];
    const float* W1  = (const float*)d_in[2];
    const float* as1 = (const float*)d_in[3];
    const float* ad1 = (const float*)d_in[4];
    const float* b1  = (const float*)d_in[5];
    const float* W2  = (const float*)d_in[6];
    const float* as2 = (const float*)d_in[7];
    const float* ad2 = (const float*)d_in[8];
    const float* b2  = (const float*)d_in[9];
    const float* dW1 = (const float*)d_in[10];
    const float* db1 = (const float*)d_in[11];
    const float* dW2 = (const float*)d_in[12];
    const float* db2 = (const float*)d_in[13];

    const int N    = in_sizes[0] / IN_DIM;
    const int E    = in_sizes[1] / 2;
    const int Etot = E + N;

    float* ws = (float*)d_ws;
    unsigned short* hxb = (unsigned short*)ws;   // N*256 bf16 (N*256 f32 slot)
    float* a_s1 = ws   + (size_t)N * C1;         // N*4
    float* a_d1 = a_s1 + (size_t)N * HEADS;      // N*4
    float* a_s2 = a_d1 + (size_t)N * HEADS;      // N
    float* a_d2 = a_s2 + (size_t)N;              // N
    float* ew1  = a_d2 + (size_t)N;              // Etot*4 (interleaved [p*4+h])
    float* ew2  = ew1  + (size_t)Etot * HEADS;   // Etot
    unsigned short* h1b = (unsigned short*)(ew2 + (size_t)Etot);  // N*256 bf16
    unsigned short* h2b = h1b + (size_t)N * C1;                   // N*64 bf16
    int* rowptr = (int*)(h2b + (size_t)N * OUT_DIM);              // N+1
    int* cursor = rowptr + (N + 1);              // N
    int* col    = cursor + N;                    // Etot
    int* row    = col    + Etot;                 // Etot
    int* psum   = row    + Etot;                 // 256
    unsigned short* W1f = (unsigned short*)(psum + 256);  // 32768 u16
    unsigned short* W2f = W1f + 64 * 64 * 8;              // 16384 u16

    const size_t needed = ((size_t)N * 428 + 257 + (size_t)Etot * 7) * 4 + 98304;
    if (ws_size < needed) return;  // loud failure signature (absmax ~0.543)

    hipMemsetAsync(rowptr, 0, (size_t)(N + 1) * sizeof(int), stream);

    const int eblk = (Etot + 255) / 256;
    const int SC   = (N + 255) / 256;            // <=256 chunks (N=50k -> 196)
    const int mblk = (N + 63) / 64;
    w1f_k  <<<16, 256, 0, stream>>>(W1, W1f);
    w2f_k  <<<8, 256, 0, stream>>>(W2, W2f);
    gemm1_k<<<mblk, 256, 0, stream>>>(x, W1f, as1, ad1, h1b, a_s1, a_d1, N);
    deg_k  <<<eblk, 256, 0, stream>>>(ei, E, Etot, rowptr);
    scanA_k<<<SC, 256, 0, stream>>>(rowptr, psum, N);
    scanB_k<<<1, 256, 0, stream>>>(psum, SC);
    scanC_k<<<SC, 256, 0, stream>>>(rowptr, cursor, psum, N);
    fill_k <<<eblk, 256, 0, stream>>>(ei, E, Etot, cursor, col, row);
    ew1_k  <<<eblk, 256, 0, stream>>>(col, row, a_s1, a_d1, ew1, Etot);
    agg1_k <<<(N + 3) / 4, 256, 0, stream>>>(rowptr, col, ew1, h1b, b1, hxb, N);
    gemm2_k<<<mblk, 256, 0, stream>>>(hxb, W2f, as2, ad2, h2b, a_s2, a_d2, N);
    ew2_k  <<<eblk, 256, 0, stream>>>(col, row, a_s2, a_d2, ew2, Etot);
    agg2_k <<<(N + 3) / 4, 256, 0, stream>>>(rowptr, col, ew2, h2b, b2,
                                             (float*)d_out, N);
    dec_k  <<<(N + 31) / 32, 256, 0, stream>>>((const float*)d_out, dW1, db1,
                                               dW2, db2,
                                               (float*)d_out + (size_t)N * OUT_DIM, N);
}